// Round 2
// baseline (145.947 us; speedup 1.0000x reference)
//
#include <hip/hip_runtime.h>
#include <math.h>

// LogPolar resample: data (32,3,512,512) f32 -> out (32,3,512,512) f32.
//
// The sampling map is data-independent and must BIT-MATCH the reference's
// float32 computation: index truncation (trunc(X), trunc(Y)) and the bounds
// mask are discontinuous decisions (the distance-PROPORTIONAL weight scheme
// jumps O(1) across integer boundaries), so we emulate every f32 op of the
// reference chain exactly:
//   - each f32 mul/add: operands exact in f64, single op, one round to f32
//   - each f32 transcendental: correctly-rounded f32 via device f64 libm
//   - pi enters as f32(pi) (jax weak-types jnp.pi to f32)
// Map computed once per thread, reused across all 96 planes.

#define HW (512 * 512)
#define PLANES 96

__global__ __launch_bounds__(256) void logpolar_kernel(
    const float* __restrict__ in, float* __restrict__ out) {
  const int pix = blockIdx.x * 256 + threadIdx.x;  // grid sized exactly
  const int i = pix >> 9;   // theta bin (row)
  const int j = pix & 511;  // radius bin (col)

  // ---- max_r = log(sqrt(512^2+512^2)/2 * 700), all in f32 steps ----
  const float sq_f   = (float)sqrt(524288.0);            // f32 sqrt (CR)
  const float half_f = sq_f * 0.5f;                      // exact
  const float prod_f = (float)((double)half_f * 700.0);  // f32 mul emulated
  const float maxr_f = (float)log((double)prod_f);       // f32 log (CR)

  // ---- rad = exp(j * max_r / 512) in f32 steps ----
  const float t1    = (float)((double)(float)j * (double)maxr_f);  // f32 mul
  const float t     = t1 * (1.0f / 512.0f);              // /512 exact (pow2)
  const float rad_f = (float)exp((double)t);             // f32 exp (CR)

  // ---- ang = i * 2.0 * f32(pi) / 512 in f32 steps ----
  const float two_i = (float)(2 * i);                    // exact (<= 1022)
  const float ang1  = (float)((double)two_i * (double)(float)M_PI);  // f32 mul
  const float ang   = ang1 * (1.0f / 512.0f);            // exact (pow2)
  const float c_f   = (float)cos((double)ang);           // f32 cos (CR)
  const float s_f   = (float)sin((double)ang);           // f32 sin (CR)

  // ---- X = 256 + rad*cos, Y = 256 - rad*sin in f32 steps ----
  const float X0 = (float)((double)rad_f * (double)c_f);
  const float Y0 = (float)((double)rad_f * (double)s_f);
  const float X  = (float)(256.0 + (double)X0);
  const float Y  = (float)(256.0 - (double)Y0);

  const bool inb =
      (X >= 0.0f) && (X < 512.0f) && (Y >= 0.0f) && (Y < 512.0f);

  // ---- corner indices + distance-proportional weights (f64; tolerance-safe)
  float wdd = 0.f, wdu = 0.f, wud = 0.f, wuu = 0.f;
  int idd = 0, idu = 0, iud = 0, iuu = 0;
  if (inb) {
    const int yd = (int)Y;  // trunc == floor for Y in [0,512)
    const int xd = (int)X;
    const int yu = min(yd + 1, 511);
    const int xu = min(xd + 1, 511);
    const double Xd = (double)X, Yd = (double)Y;
    const double dyd = (Yd - (double)yd) * (Yd - (double)yd);
    const double dyu = (Yd - (double)yu) * (Yd - (double)yu);
    const double dxd = (Xd - (double)xd) * (Xd - (double)xd);
    const double dxu = (Xd - (double)xu) * (Xd - (double)xu);
    const double dd = dyd + dxd;
    const double du = dyd + dxu;
    const double ud = dyu + dxd;
    const double uu = dyu + dxu;
    const double inv = 1.0 / (dd + du + ud + uu);
    wdd = (float)(dd * inv);
    wdu = (float)(du * inv);
    wud = (float)(ud * inv);
    wuu = (float)(uu * inv);
    idd = yd * 512 + xd;
    idu = yd * 512 + xu;
    iud = yu * 512 + xd;
    iuu = yu * 512 + xu;
  }

  // ---- plane loop: 4 gathers + 1 coalesced store per plane ----
  const float* __restrict__ ip = in;
  float* __restrict__ op = out + pix;
#pragma unroll 4
  for (int p = 0; p < PLANES; ++p) {
    float v = 0.0f;
    if (inb) {
      v = wdd * ip[idd] + wdu * ip[idu] + wud * ip[iud] + wuu * ip[iuu];
    }
    *op = v;
    ip += HW;
    op += HW;
  }
}

extern "C" void kernel_launch(void* const* d_in, const int* in_sizes, int n_in,
                              void* d_out, int out_size, void* d_ws,
                              size_t ws_size, hipStream_t stream) {
  const float* in = (const float*)d_in[0];
  float* out = (float*)d_out;
  // 512*512 output pixels / 256 threads = 1024 blocks (exact)
  logpolar_kernel<<<dim3(1024), dim3(256), 0, stream>>>(in, out);
}

// Round 3
// 114.423 us; speedup vs baseline: 1.2755x; 1.2755x over previous
//
#include <hip/hip_runtime.h>
#include <math.h>

// LogPolar resample: data (32,3,512,512) f32 -> out (32,3,512,512) f32.
//
// Two-kernel structure:
//  1) map_kernel (1024 blocks): per output pixel, emulate the reference's
//     float32 map chain bit-exactly (f64 libm for correctly-rounded f32
//     transcendentals; every f32 mul/add rounded once) -> float4 weights +
//     packed corner offsets into d_ws (6.3 MB). Discontinuous trunc/mask
//     decisions must match the np reference exactly (weights are
//     distance-PROPORTIONAL -> O(1) jump across integer boundaries).
//  2) resample_kernel (8192 blocks = 32768 waves): each block handles 256
//     pixels x 12 planes. XCD k (blockIdx&7) owns planes [12k,12k+12) so each
//     per-XCD L2 only ever sees its own 12 planes (kills cross-XCD re-fetch
//     seen in R2: FETCH was 2.2x input). Output stored non-temporally
//     (never re-read; keep L2 for gathers).
//
// R2 post-mortem: 1024 blocks = 4096 waves was latency-bound (occupancy 18%,
// VALUBusy 3.4%, HBM 19%). Map precompute lets us split planes across blocks
// without multiplying the f64-trig cost.

#define HW (512 * 512)
#define NPIX (512 * 512)
#define PLANES 96
#define PPB 12  // planes per resample block

// ---------------- map kernel ----------------
__global__ __launch_bounds__(256) void map_kernel(float4* __restrict__ wmap,
                                                  int2* __restrict__ imap) {
  const int pix = blockIdx.x * 256 + threadIdx.x;
  const int i = pix >> 9;   // theta bin
  const int j = pix & 511;  // radius bin

  // max_r = log(sqrt(512^2+512^2)/2 * 700), all in f32 steps
  const float sq_f = (float)sqrt(524288.0);             // f32 sqrt (CR)
  const float half_f = sq_f * 0.5f;                     // exact
  const float prod_f = (float)((double)half_f * 700.0); // f32 mul emulated
  const float maxr_f = (float)log((double)prod_f);      // f32 log (CR)

  // rad = exp(j * max_r / 512) in f32 steps
  const float t1 = (float)((double)(float)j * (double)maxr_f); // f32 mul
  const float t = t1 * (1.0f / 512.0f);                        // exact (pow2)
  const float rad_f = (float)exp((double)t);                   // f32 exp (CR)

  // ang = i * 2.0 * f32(pi) / 512 in f32 steps
  const float two_i = (float)(2 * i);  // exact
  const float ang1 = (float)((double)two_i * (double)(float)M_PI); // f32 mul
  const float ang = ang1 * (1.0f / 512.0f);                        // exact
  const float c_f = (float)cos((double)ang); // f32 cos (CR)
  const float s_f = (float)sin((double)ang); // f32 sin (CR)

  // X = 256 + rad*cos, Y = 256 - rad*sin in f32 steps
  const float X0 = (float)((double)rad_f * (double)c_f);
  const float Y0 = (float)((double)rad_f * (double)s_f);
  const float X = (float)(256.0 + (double)X0);
  const float Y = (float)(256.0 - (double)Y0);

  const bool inb = (X >= 0.0f) && (X < 512.0f) && (Y >= 0.0f) && (Y < 512.0f);

  float4 w = make_float4(0.f, 0.f, 0.f, 0.f);
  int2 e = make_int2(-1, 0);
  if (inb) {
    const int yd = (int)Y;  // trunc == floor for Y in [0,512)
    const int xd = (int)X;
    const int yu = min(yd + 1, 511);
    const int xu = min(xd + 1, 511);
    const double Xd = (double)X, Yd = (double)Y;
    const double dyd = (Yd - (double)yd) * (Yd - (double)yd);
    const double dyu = (Yd - (double)yu) * (Yd - (double)yu);
    const double dxd = (Xd - (double)xd) * (Xd - (double)xd);
    const double dxu = (Xd - (double)xu) * (Xd - (double)xu);
    const double dd = dyd + dxd;
    const double du = dyd + dxu;
    const double ud = dyu + dxd;
    const double uu = dyu + dxu;
    const double inv = 1.0 / (dd + du + ud + uu);
    w.x = (float)(dd * inv);
    w.y = (float)(du * inv);
    w.z = (float)(ud * inv);
    w.w = (float)(uu * inv);
    e.x = yd * 512 + xd;
    // low 16 bits: +x step (0 or 1); high 16 bits: +y step (0 or 512)
    e.y = (xu - xd) | ((yu - yd) ? (512 << 16) : 0);
  }
  wmap[pix] = w;
  imap[pix] = e;
}

// ---------------- resample kernel ----------------
__global__ __launch_bounds__(256) void resample_kernel(
    const float* __restrict__ in, float* __restrict__ out,
    const float4* __restrict__ wmap, const int2* __restrict__ imap) {
  const int f = blockIdx.x;          // 0..8191
  const int pixblock = f >> 3;       // 0..1023
  const int p0 = (f & 7) * PPB;      // XCD k (round-robin) -> planes [12k,12k+12)
  const int pix = pixblock * 256 + (int)threadIdx.x;

  const float4 w = wmap[pix];
  const int2 e = imap[pix];

  float* op = out + (size_t)p0 * HW + pix;
  if (e.x < 0) {
#pragma unroll
    for (int p = 0; p < PPB; ++p) {
      __builtin_nontemporal_store(0.0f, op);
      op += HW;
    }
    return;
  }
  const int i00 = e.x;
  const int dx = e.y & 0xffff;
  const int dy = e.y >> 16;
  const int i01 = i00 + dx;
  const int i10 = i00 + dy;
  const int i11 = i00 + dy + dx;
  const float* ip = in + (size_t)p0 * HW;
#pragma unroll
  for (int p = 0; p < PPB; ++p) {
    const float v = w.x * ip[i00] + w.y * ip[i01] + w.z * ip[i10] + w.w * ip[i11];
    __builtin_nontemporal_store(v, op);
    ip += HW;
    op += HW;
  }
}

// ---------------- fallback: proven R2 monolithic kernel ----------------
__global__ __launch_bounds__(256) void logpolar_mono(
    const float* __restrict__ in, float* __restrict__ out) {
  const int pix = blockIdx.x * 256 + threadIdx.x;
  const int i = pix >> 9;
  const int j = pix & 511;

  const float sq_f = (float)sqrt(524288.0);
  const float half_f = sq_f * 0.5f;
  const float prod_f = (float)((double)half_f * 700.0);
  const float maxr_f = (float)log((double)prod_f);
  const float t1 = (float)((double)(float)j * (double)maxr_f);
  const float t = t1 * (1.0f / 512.0f);
  const float rad_f = (float)exp((double)t);
  const float two_i = (float)(2 * i);
  const float ang1 = (float)((double)two_i * (double)(float)M_PI);
  const float ang = ang1 * (1.0f / 512.0f);
  const float c_f = (float)cos((double)ang);
  const float s_f = (float)sin((double)ang);
  const float X0 = (float)((double)rad_f * (double)c_f);
  const float Y0 = (float)((double)rad_f * (double)s_f);
  const float X = (float)(256.0 + (double)X0);
  const float Y = (float)(256.0 - (double)Y0);

  const bool inb = (X >= 0.0f) && (X < 512.0f) && (Y >= 0.0f) && (Y < 512.0f);

  float wdd = 0.f, wdu = 0.f, wud = 0.f, wuu = 0.f;
  int idd = 0, idu = 0, iud = 0, iuu = 0;
  if (inb) {
    const int yd = (int)Y;
    const int xd = (int)X;
    const int yu = min(yd + 1, 511);
    const int xu = min(xd + 1, 511);
    const double Xd = (double)X, Yd = (double)Y;
    const double dyd = (Yd - (double)yd) * (Yd - (double)yd);
    const double dyu = (Yd - (double)yu) * (Yd - (double)yu);
    const double dxd = (Xd - (double)xd) * (Xd - (double)xd);
    const double dxu = (Xd - (double)xu) * (Xd - (double)xu);
    const double dd = dyd + dxd;
    const double du = dyd + dxu;
    const double ud = dyu + dxd;
    const double uu = dyu + dxu;
    const double inv = 1.0 / (dd + du + ud + uu);
    wdd = (float)(dd * inv);
    wdu = (float)(du * inv);
    wud = (float)(ud * inv);
    wuu = (float)(uu * inv);
    idd = yd * 512 + xd;
    idu = yd * 512 + xu;
    iud = yu * 512 + xd;
    iuu = yu * 512 + xu;
  }

  const float* __restrict__ ip = in;
  float* __restrict__ op = out + pix;
#pragma unroll 4
  for (int p = 0; p < PLANES; ++p) {
    float v = 0.0f;
    if (inb) {
      v = wdd * ip[idd] + wdu * ip[idu] + wud * ip[iud] + wuu * ip[iuu];
    }
    *op = v;
    ip += HW;
    op += HW;
  }
}

extern "C" void kernel_launch(void* const* d_in, const int* in_sizes, int n_in,
                              void* d_out, int out_size, void* d_ws,
                              size_t ws_size, hipStream_t stream) {
  const float* in = (const float*)d_in[0];
  float* out = (float*)d_out;

  const size_t wmap_bytes = (size_t)NPIX * sizeof(float4);  // 4 MiB
  const size_t imap_bytes = (size_t)NPIX * sizeof(int2);    // 2 MiB
  if (ws_size >= wmap_bytes + imap_bytes) {
    float4* wmap = (float4*)d_ws;
    int2* imap = (int2*)((char*)d_ws + wmap_bytes);
    map_kernel<<<dim3(NPIX / 256), dim3(256), 0, stream>>>(wmap, imap);
    resample_kernel<<<dim3(NPIX / 256 * (PLANES / PPB)), dim3(256), 0, stream>>>(
        in, out, wmap, imap);
  } else {
    // workspace too small: proven monolithic fallback (R2)
    logpolar_mono<<<dim3(NPIX / 256), dim3(256), 0, stream>>>(in, out);
  }
}

// Round 4
// 101.347 us; speedup vs baseline: 1.4401x; 1.1290x over previous
//
#include <hip/hip_runtime.h>
#include <math.h>

// LogPolar resample: data (32,3,512,512) f32 -> out (32,3,512,512) f32.
//
// R4 structure:
//  1) table_kernel (2 blocks): the map factorizes! rad=exp(j*max_r/512)
//     depends only on j; cos/sin(ang(i)) only on i. Only 3*512 correctly-
//     rounded-f32 transcendentals exist -> 6 KB tables in d_ws, computed via
//     f64 libm (CR f32 emulation, bit-identical to the R2 chain that passed).
//  2) resample_kernel (16384 blocks = 65k waves): rebuilds X,Y from tables
//     with NATIVE f32 ops -- __fmul_rn/__fadd_rn are correctly rounded and
//     contraction-proof, which is exactly "exact f64 op, round once", so X,Y
//     (and thus every discontinuous trunc/mask decision) are BIT-IDENTICAL
//     to R2. Weights stay in f64 (identical to R2). PPB=6 planes/block, 16
//     plane-groups; blockIdx&7 = XCD -> each XCD L2 sees only its 12 planes.
//     Full unroll = 24 independent gathers in flight/wave for latency hiding.
//
// R3 post-mortem: traffic near-ideal (168 MB) but HBM 11%, VALU 2.3%, occ 37%
// -> latency/gather-request-bound. Gather-line-request floor ~= 36 us; attack
// the gap with 2x waves, deeper MLP, and by deleting the map kernel+traffic.

#define HW (512 * 512)
#define NPIX (512 * 512)
#define PLANES 96
#define PPB 6   // planes per resample block
#define NG 16   // plane groups (PLANES/PPB)

// ---------------- table kernel: 512 entries of rad/cos/sin ----------------
__global__ __launch_bounds__(256) void table_kernel(float* __restrict__ radT,
                                                    float* __restrict__ cT,
                                                    float* __restrict__ sT) {
  const int t = blockIdx.x * 256 + threadIdx.x;  // 0..511

  // max_r = log(sqrt(512^2+512^2)/2 * 700), all in f32 steps (CR via f64)
  const float sq_f = (float)sqrt(524288.0);             // f32 sqrt (CR)
  const float half_f = sq_f * 0.5f;                     // exact
  const float prod_f = (float)((double)half_f * 700.0); // f32 mul emulated
  const float maxr_f = (float)log((double)prod_f);      // f32 log (CR)

  // rad = exp(t * max_r / 512) in f32 steps
  const float t1 = (float)((double)(float)t * (double)maxr_f); // f32 mul
  const float tt = t1 * (1.0f / 512.0f);                       // exact (pow2)
  radT[t] = (float)exp((double)tt);                            // f32 exp (CR)

  // ang = t * 2.0 * f32(pi) / 512 in f32 steps
  const float two_i = (float)(2 * t);  // exact
  const float ang1 = (float)((double)two_i * (double)(float)M_PI); // f32 mul
  const float ang = ang1 * (1.0f / 512.0f);                        // exact
  cT[t] = (float)cos((double)ang);  // f32 cos (CR)
  sT[t] = (float)sin((double)ang);  // f32 sin (CR)
}

// ---------------- resample kernel ----------------
__global__ __launch_bounds__(256) void resample_kernel(
    const float* __restrict__ in, float* __restrict__ out,
    const float* __restrict__ radT, const float* __restrict__ cT,
    const float* __restrict__ sT) {
  const int g = blockIdx.x & (NG - 1);   // plane group; g&7 = XCD
  const int pixblock = blockIdx.x >> 4;  // 0..1023
  const int pix = pixblock * 256 + (int)threadIdx.x;
  const int i = pix >> 9;   // theta bin (block-uniform)
  const int j = pix & 511;  // radius bin

  const float rad = radT[j];
  const float c = cT[i];
  const float s = sT[i];

  // Native f32 ops == "exact in f64, round once" (correctly rounded,
  // contraction-proof) -> X,Y bit-identical to the R2 passing chain.
  const float X = __fadd_rn(256.0f, __fmul_rn(rad, c));
  const float Y = __fsub_rn(256.0f, __fmul_rn(rad, s));

  const int p0 = g * PPB;
  float* op = out + (size_t)p0 * HW + pix;

  const bool inb = (X >= 0.0f) && (X < 512.0f) && (Y >= 0.0f) && (Y < 512.0f);
  if (!inb) {
#pragma unroll
    for (int p = 0; p < PPB; ++p) {
      __builtin_nontemporal_store(0.0f, op);
      op += HW;
    }
    return;
  }

  // corner indices + f64 weights (bit-identical to R2)
  const int yd = (int)Y;  // trunc == floor for Y in [0,512)
  const int xd = (int)X;
  const int yu = min(yd + 1, 511);
  const int xu = min(xd + 1, 511);
  const double Xd = (double)X, Yd = (double)Y;
  const double dyd = (Yd - (double)yd) * (Yd - (double)yd);
  const double dyu = (Yd - (double)yu) * (Yd - (double)yu);
  const double dxd = (Xd - (double)xd) * (Xd - (double)xd);
  const double dxu = (Xd - (double)xu) * (Xd - (double)xu);
  const double dd = dyd + dxd;
  const double du = dyd + dxu;
  const double ud = dyu + dxd;
  const double uu = dyu + dxu;
  const double inv = 1.0 / (dd + du + ud + uu);
  const float wdd = (float)(dd * inv);
  const float wdu = (float)(du * inv);
  const float wud = (float)(ud * inv);
  const float wuu = (float)(uu * inv);

  const int i00 = yd * 512 + xd;
  const int i01 = yd * 512 + xu;
  const int i10 = yu * 512 + xd;
  const int i11 = yu * 512 + xu;

  const float* ip = in + (size_t)p0 * HW;
#pragma unroll
  for (int p = 0; p < PPB; ++p) {
    const float v =
        wdd * ip[i00] + wdu * ip[i01] + wud * ip[i10] + wuu * ip[i11];
    __builtin_nontemporal_store(v, op);
    ip += HW;
    op += HW;
  }
}

// ---------------- fallback: proven R2 monolithic kernel ----------------
__global__ __launch_bounds__(256) void logpolar_mono(
    const float* __restrict__ in, float* __restrict__ out) {
  const int pix = blockIdx.x * 256 + threadIdx.x;
  const int i = pix >> 9;
  const int j = pix & 511;

  const float sq_f = (float)sqrt(524288.0);
  const float half_f = sq_f * 0.5f;
  const float prod_f = (float)((double)half_f * 700.0);
  const float maxr_f = (float)log((double)prod_f);
  const float t1 = (float)((double)(float)j * (double)maxr_f);
  const float t = t1 * (1.0f / 512.0f);
  const float rad_f = (float)exp((double)t);
  const float two_i = (float)(2 * i);
  const float ang1 = (float)((double)two_i * (double)(float)M_PI);
  const float ang = ang1 * (1.0f / 512.0f);
  const float c_f = (float)cos((double)ang);
  const float s_f = (float)sin((double)ang);
  const float X0 = (float)((double)rad_f * (double)c_f);
  const float Y0 = (float)((double)rad_f * (double)s_f);
  const float X = (float)(256.0 + (double)X0);
  const float Y = (float)(256.0 - (double)Y0);

  const bool inb = (X >= 0.0f) && (X < 512.0f) && (Y >= 0.0f) && (Y < 512.0f);

  float wdd = 0.f, wdu = 0.f, wud = 0.f, wuu = 0.f;
  int idd = 0, idu = 0, iud = 0, iuu = 0;
  if (inb) {
    const int yd = (int)Y;
    const int xd = (int)X;
    const int yu = min(yd + 1, 511);
    const int xu = min(xd + 1, 511);
    const double Xd = (double)X, Yd = (double)Y;
    const double dyd = (Yd - (double)yd) * (Yd - (double)yd);
    const double dyu = (Yd - (double)yu) * (Yd - (double)yu);
    const double dxd = (Xd - (double)xd) * (Xd - (double)xd);
    const double dxu = (Xd - (double)xu) * (Xd - (double)xu);
    const double dd = dyd + dxd;
    const double du = dyd + dxu;
    const double ud = dyu + dxd;
    const double uu = dyu + dxu;
    const double inv = 1.0 / (dd + du + ud + uu);
    wdd = (float)(dd * inv);
    wdu = (float)(du * inv);
    wud = (float)(ud * inv);
    wuu = (float)(uu * inv);
    idd = yd * 512 + xd;
    idu = yd * 512 + xu;
    iud = yu * 512 + xd;
    iuu = yu * 512 + xu;
  }

  const float* __restrict__ ip = in;
  float* __restrict__ op = out + pix;
#pragma unroll 4
  for (int p = 0; p < PLANES; ++p) {
    float v = 0.0f;
    if (inb) {
      v = wdd * ip[idd] + wdu * ip[idu] + wud * ip[iud] + wuu * ip[iuu];
    }
    *op = v;
    ip += HW;
    op += HW;
  }
}

extern "C" void kernel_launch(void* const* d_in, const int* in_sizes, int n_in,
                              void* d_out, int out_size, void* d_ws,
                              size_t ws_size, hipStream_t stream) {
  const float* in = (const float*)d_in[0];
  float* out = (float*)d_out;

  const size_t table_bytes = 3 * 512 * sizeof(float);  // 6 KB
  if (ws_size >= table_bytes) {
    float* radT = (float*)d_ws;
    float* cT = radT + 512;
    float* sT = cT + 512;
    table_kernel<<<dim3(2), dim3(256), 0, stream>>>(radT, cT, sT);
    resample_kernel<<<dim3((NPIX / 256) * NG), dim3(256), 0, stream>>>(
        in, out, radT, cT, sT);
  } else {
    logpolar_mono<<<dim3(NPIX / 256), dim3(256), 0, stream>>>(in, out);
  }
}